// Round 3
// baseline (612.804 us; speedup 1.0000x reference)
//
#include <hip/hip_runtime.h>
#include <hip/hip_cooperative_groups.h>
#include <math.h>

namespace cg = cooperative_groups;

#define GSZ 52
#define NA 3
#define NCLS 80
#define CH 85                    // 5 + NCLS
#define NCA (GSZ*GSZ*NA)         // 8112 cell-anchors per batch
#define MAXGT 64
#define MCHUNK 32                // noobj units per batch: 32 x 256 = 8192 >= 8112
#define CLSU 16                  // cls units per batch: 16 x 4 waves = 64 slots

// fast softplus: max(x,0) + log(1+exp(-|x|)) with HW-approx exp/log.
__device__ __forceinline__ float softplus_fast(float x) {
    return fmaxf(x, 0.0f) + __logf(1.0f + __expf(-fabsf(x)));
}

// Rare path: full record read + class scan for an obj record.
__device__ __forceinline__ void emit_gt(const float* __restrict__ tg, int glob,
                                        int* cnt, float4* __restrict__ gtbox,
                                        int2* __restrict__ gtinfo) {
    const float* r = tg + (size_t)glob * CH;
    int b    = glob / NCA;
    int nloc = glob - b * NCA;
    int cid = 0;
#pragma unroll 16
    for (int c = 0; c < NCLS; c++) if (r[5 + c] > 0.5f) cid = c;
    int pos = atomicAdd(cnt + b, 1);
    if (pos < MAXGT) {
        gtbox[b * MAXGT + pos]  = make_float4(r[0], r[1], r[2], r[3]);
        gtinfo[b * MAXGT + pos] = make_int2(nloc, cid);
    }
}

// Single cooperative kernel: init -> parity-split scan -> noobj+cls -> final.
// grid.sync() between phases replaces 4 kernel launches + full-GPU drains.
__global__ __launch_bounds__(256) void k_all(
    const float* __restrict__ tg, const float* __restrict__ pr,
    const float* __restrict__ anchors, int B, int* cnt,
    float4* __restrict__ gtbox, int2* __restrict__ gtinfo,
    float4* __restrict__ boxdec, float* __restrict__ confdec,
    float* __restrict__ partial, float4* __restrict__ cls4,
    float* __restrict__ out)
{
    cg::grid_group grid = cg::this_grid();
    __shared__ float4 sbox[MAXGT];
    __shared__ int    sidx[MAXGT];
    __shared__ float  swsum[4];
    __shared__ double sred[4 * 5];

    const int tid  = threadIdx.x;
    const int bid  = blockIdx.x;
    const int G    = gridDim.x;
    const int gtid = bid * 256 + tid;
    const int nrec = B * NCA;

    // ---- phase 0: zero GT counters ----
    if (bid == 0 && tid < B) cnt[tid] = 0;
    grid.sync();

    // ---- phase 1: parity-split scan (2 threads per record) ----
    // even thread: 4 box-logit loads + decode + boxdec write
    // odd  thread: pred-conf + target-conf loads + confdec write + rare GT-emit
    {
        const int stride = G * 256;
        const int ntask  = 2 * nrec;
        for (int t = gtid; t < ntask; t += stride) {
            int rec = t >> 1;
            const float* rp = pr + (size_t)rec * CH;
            if (t & 1) {
                float pc     = rp[4];
                float conf_t = tg[(size_t)rec * CH + 4];
                confdec[rec] = pc;
                if (conf_t > 0.0f) emit_gt(tg, rec, cnt, gtbox, gtinfo);
            } else {
                float r0 = rp[0], r1 = rp[1], r2 = rp[2], r3 = rp[3];
                int b    = rec / NCA;
                int n    = rec - b * NCA;
                int a    = n % NA;
                int cell = n / NA;
                int gi = cell / GSZ, gj = cell % GSZ;
                float aw = anchors[2 * a], ah = anchors[2 * a + 1];
                float sx = __builtin_amdgcn_rcpf(1.0f + __expf(-r0));
                float sy = __builtin_amdgcn_rcpf(1.0f + __expf(-r1));
                float bx = (sx + (float)gj) * 8.0f;
                float by = (sy + (float)gi) * 8.0f;
                float bw = __expf(r2) * aw;
                float bh = __expf(r3) * ah;
                boxdec[rec] = make_float4(bx, by, bw, bh);
            }
        }
    }
    grid.sync();

    // ---- phase 2: noobj IoU units + cls units ----
    {
        const int nu    = B * MCHUNK;          // noobj units
        const int units = nu + B * CLSU;       // + cls units
        for (int u = bid; u < units; u += G) {
            if (u < nu) {
                int b     = u >> 5;            // / MCHUNK
                int chunk = u & (MCHUNK - 1);
                int n = chunk * 256 + tid;
                int m = min(cnt[b], MAXGT);
                if (tid < m) {
                    sbox[tid] = gtbox[b * MAXGT + tid];
                    sidx[tid] = gtinfo[b * MAXGT + tid].x;
                }
                __syncthreads();

                float v = 0.0f;
                if (n < NCA) {
                    size_t rec = (size_t)b * NCA + n;
                    float4 pb = boxdec[rec];
                    float  pc = confdec[rec];
                    float px0 = pb.x - pb.z * 0.5f, px1 = pb.x + pb.z * 0.5f;
                    float py0 = pb.y - pb.w * 0.5f, py1 = pb.y + pb.w * 0.5f;
                    float areap = pb.z * pb.w;

                    float best = 0.0f;
                    bool isobj = false;
                    for (int k = 0; k < m; k++) {
                        float4 g = sbox[k];
                        isobj |= (sidx[k] == n);
                        float ix = fminf(px1, g.x + g.z * 0.5f) - fmaxf(px0, g.x - g.z * 0.5f);
                        float iy = fminf(py1, g.y + g.w * 0.5f) - fmaxf(py0, g.y - g.w * 0.5f);
                        float inter = fmaxf(ix, 0.0f) * fmaxf(iy, 0.0f);
                        float uu = areap + g.z * g.w - inter + 1e-9f;
                        best = fmaxf(best, inter * __builtin_amdgcn_rcpf(uu));
                    }
                    if (!isobj && best < 0.6f) v = softplus_fast(pc);
                }

                int lane = tid & 63;
                int wv   = tid >> 6;
                for (int off = 32; off > 0; off >>= 1) v += __shfl_down(v, off);
                if (lane == 0) swsum[wv] = v;
                __syncthreads();
                if (tid == 0)
                    partial[u] = swsum[0] + swsum[1] + swsum[2] + swsum[3];
            } else {
                int wv   = tid >> 6;
                int lane = tid & 63;
                int slot = (u - nu) * 4 + wv;
                int b    = slot >> 6;          // / MAXGT
                int k    = slot & (MAXGT - 1);

                float4 resv = make_float4(0.f, 0.f, 0.f, 0.f);
                int m = min(cnt[b], MAXGT);
                if (k < m) {
                    float4 g  = gtbox[slot];
                    int2 info = gtinfo[slot];
                    int n = info.x, cid = info.y;
                    size_t rec = (size_t)b * NCA + n;
                    const float* cl = pr + rec * CH + 5;

                    float x0 = cl[lane];
                    float cls = softplus_fast(x0) - (lane == cid ? x0 : 0.0f);
                    if (lane < NCLS - 64) {
                        float x1 = cl[64 + lane];
                        cls += softplus_fast(x1) - ((64 + lane) == cid ? x1 : 0.0f);
                    }
                    for (int off = 32; off > 0; off >>= 1) cls += __shfl_down(cls, off);

                    if (lane == 0) {
                        float4 pb = boxdec[rec];
                        float  pc = confdec[rec];
                        int a    = n % NA;
                        int cell = n / NA;
                        int gi = cell / GSZ, gj = cell % GSZ;
                        float aw = anchors[2 * a], ah = anchors[2 * a + 1];

                        float scale = 2.0f - (g.z * (1.0f / 416.0f)) * (g.w * (1.0f / 416.0f));
                        float dx = (pb.x * 0.125f - (float)gj) - (g.x * 0.125f - (float)gj);
                        float dy = (pb.y * 0.125f - (float)gi) - (g.y * 0.125f - (float)gi);
                        float txty = (dx * dx + dy * dy) * scale;

                        float rw = __builtin_amdgcn_rcpf(aw), rh = __builtin_amdgcn_rcpf(ah);
                        float pwr = fminf(fmaxf(pb.z * rw, 1e-9f), 1e9f);
                        float phr = fminf(fmaxf(pb.w * rh, 1e-9f), 1e9f);
                        float twr = fminf(fmaxf(g.z  * rw, 1e-9f), 1e9f);
                        float thr = fminf(fmaxf(g.w  * rh, 1e-9f), 1e9f);
                        float dw = __logf(pwr) - __logf(twr);
                        float dh = __logf(phr) - __logf(thr);
                        float twth = (dw * dw + dh * dh) * scale;

                        float obj = softplus_fast(pc) - pc;
                        resv = make_float4(txty, twth, obj, cls);
                    }
                }
                if (lane == 0) cls4[slot] = resv;
            }
            __syncthreads();   // protect sbox reuse across grid-stride iterations
        }
    }
    grid.sync();

    // ---- phase 3: block 0 final reduction ----
    if (bid == 0) {
        const int np = B * MCHUNK;
        const int ns = B * MAXGT;
        double acc[5] = {0, 0, 0, 0, 0};   // txty, twth, noobj, obj, cls
        for (int i = tid; i < np; i += 256) acc[2] += (double)partial[i];
        for (int i = tid; i < ns; i += 256) {
            float4 v = cls4[i];
            acc[0] += (double)v.x; acc[1] += (double)v.y;
            acc[3] += (double)v.z; acc[4] += (double)v.w;
        }
        int lane = tid & 63;
        int wv   = tid >> 6;
#pragma unroll
        for (int i = 0; i < 5; i++) {
            double v = acc[i];
            for (int off = 32; off > 0; off >>= 1) v += __shfl_down(v, off);
            if (lane == 0) sred[wv * 5 + i] = v;
        }
        __syncthreads();
        if (tid == 0) {
            double tot = 0.0;
#pragma unroll
            for (int i = 0; i < 5; i++) {
                double r = (sred[i] + sred[5 + i] + sred[10 + i] + sred[15 + i]) / (double)B;
                out[i] = (float)r;
                tot += r;
            }
            out[5] = (float)tot;
        }
    }
}

extern "C" void kernel_launch(void* const* d_in, const int* in_sizes, int n_in,
                              void* d_out, int out_size, void* d_ws, size_t ws_size,
                              hipStream_t stream) {
    const float* preds   = (const float*)d_in[0];
    const float* targets = (const float*)d_in[1];
    const float* anchors = (const float*)d_in[2];
    float* out = (float*)d_out;

    int B = in_sizes[0] / (NCA * CH);        // 32
    int nrec = B * NCA;                      // 259584
    int np = MCHUNK * B;                     // 1024
    int ns = B * MAXGT;                      // 2048

    // ws layout: cnt | gtbox | gtinfo | partial | boxdec | confdec | cls4
    char* ws = (char*)d_ws;
    size_t off = 0;
    int*    cnt     = (int*)(ws + off);      off += 128;
    float4* gtbox   = (float4*)(ws + off);   off += (size_t)ns * sizeof(float4);
    int2*   gtinfo  = (int2*)(ws + off);     off += (size_t)ns * sizeof(int2);
    float*  partial = (float*)(ws + off);    off += (size_t)np * sizeof(float);
    off = (off + 15) & ~(size_t)15;
    float4* boxdec  = (float4*)(ws + off);   off += (size_t)nrec * sizeof(float4);
    float*  confdec = (float*)(ws + off);    off += (size_t)nrec * sizeof(float);
    off = (off + 15) & ~(size_t)15;
    float4* cls4    = (float4*)(ws + off);   off += (size_t)ns * sizeof(float4);

    // Cooperative grid: max co-resident blocks (cached).
    static int G = 0;
    if (G == 0) {
        hipDeviceProp_t prop;
        hipGetDeviceProperties(&prop, 0);
        int perCU = 0;
        hipOccupancyMaxActiveBlocksPerMultiprocessor(&perCU, (const void*)k_all, 256, 0);
        if (perCU < 1) perCU = 1;
        G = prop.multiProcessorCount * perCU;
        if (G < 256) G = 256;
        if (G > 4096) G = 4096;
    }

    void* args[] = {(void*)&targets, (void*)&preds, (void*)&anchors, (void*)&B,
                    (void*)&cnt, (void*)&gtbox, (void*)&gtinfo,
                    (void*)&boxdec, (void*)&confdec,
                    (void*)&partial, (void*)&cls4, (void*)&out};
    hipLaunchCooperativeKernel((const void*)k_all, dim3(G), dim3(256),
                               args, 0, stream);
}

// Round 4
// 291.385 us; speedup vs baseline: 2.1031x; 2.1031x over previous
//
#include <hip/hip_runtime.h>
#include <math.h>

#define GSZ 52
#define NA 3
#define NCLS 80
#define CH 85                    // 5 + NCLS
#define NCA (GSZ*GSZ*NA)         // 8112 cell-anchors per batch
#define MAXGT 64
#define MCHUNK 32                // noobj units per batch: 32 x 256 = 8192 >= 8112
#define CLSU 16                  // cls units per batch: 16 x 4 waves = 64 slots

// L1-bypassing read: agent-scope relaxed load is serviced by L2/LLC directly
// (per-CU L1 is not agent-coherent), sidestepping the per-CU L1 MSHR limit
// that caps scattered-load concurrency. Data has zero reuse -> no L1 loss.
__device__ __forceinline__ float ld_agent(const float* p) {
    return __hip_atomic_load(p, __ATOMIC_RELAXED, __HIP_MEMORY_SCOPE_AGENT);
}

// fast softplus: max(x,0) + log(1+exp(-|x|)) with HW-approx exp/log.
__device__ __forceinline__ float softplus_fast(float x) {
    return fmaxf(x, 0.0f) + __logf(1.0f + __expf(-fabsf(x)));
}

__global__ void k_init(int* cnt) {
    // cnt[0..31] = per-batch GT counters, cnt[32] = k_nc completion counter
    if (threadIdx.x < 64) cnt[threadIdx.x] = 0;
}

// Rare path: full record read + class scan for an obj record.
__device__ __forceinline__ void emit_gt(const float* __restrict__ tg, int glob,
                                        int* cnt, float4* __restrict__ gtbox,
                                        int2* __restrict__ gtinfo) {
    const float* r = tg + (size_t)glob * CH;
    int b    = glob / NCA;
    int nloc = glob - b * NCA;
    int cid = 0;
#pragma unroll 16
    for (int c = 0; c < NCLS; c++) if (r[5 + c] > 0.5f) cid = c;
    int pos = atomicAdd(cnt + b, 1);
    if (pos < MAXGT) {
        gtbox[b * MAXGT + pos]  = make_float4(r[0], r[1], r[2], r[3]);
        gtinfo[b * MAXGT + pos] = make_int2(nloc, cid);
    }
}

// Streaming pass over both tensors: 1 thread = 1 record, 6 L1-bypass loads
// issued back-to-back before any dependent compute.
__global__ __launch_bounds__(256) void k_scan(
    const float* __restrict__ tg, const float* __restrict__ pr,
    const float* __restrict__ anchors, int nrec, int* cnt,
    float4* __restrict__ gtbox, int2* __restrict__ gtinfo,
    float4* __restrict__ boxdec, float* __restrict__ confdec) {
    int rec = blockIdx.x * 256 + threadIdx.x;
    if (rec >= nrec) return;

    const float* rp = pr + (size_t)rec * CH;
    // issue all 6 independent loads first (L2-direct, deep miss queue)
    float r0 = ld_agent(rp + 0);
    float r1 = ld_agent(rp + 1);
    float r2 = ld_agent(rp + 2);
    float r3 = ld_agent(rp + 3);
    float pc = ld_agent(rp + 4);
    float conf_t = ld_agent(tg + (size_t)rec * CH + 4);

    int b    = rec / NCA;
    int n    = rec - b * NCA;
    int a    = n % NA;
    int cell = n / NA;
    int gi = cell / GSZ, gj = cell % GSZ;
    float aw = anchors[2 * a], ah = anchors[2 * a + 1];

    float sx = __builtin_amdgcn_rcpf(1.0f + __expf(-r0));
    float sy = __builtin_amdgcn_rcpf(1.0f + __expf(-r1));
    float bx = (sx + (float)gj) * 8.0f;
    float by = (sy + (float)gi) * 8.0f;
    float bw = __expf(r2) * aw;
    float bh = __expf(r3) * ah;

    boxdec[rec]  = make_float4(bx, by, bw, bh);
    confdec[rec] = pc;

    if (conf_t > 0.0f) emit_gt(tg, rec, cnt, gtbox, gtinfo);
}

// Fused noobj + cls kernel with last-block final reduction (replaces the
// separate k_final launch; device-scope atomics + threadfence per G16).
__global__ __launch_bounds__(256) void k_nc(
    const float* __restrict__ pr,
    const float* __restrict__ anchors,
    int* __restrict__ cnt,                 // [32]=completion counter
    const float4* __restrict__ gtbox,
    const int2* __restrict__ gtinfo,
    const float4* __restrict__ boxdec,
    const float* __restrict__ confdec,
    float* __restrict__ partial,
    float4* __restrict__ cls4,
    int B, float* __restrict__ out) {
    __shared__ float4 sbox[MAXGT];
    __shared__ int    sidx[MAXGT];
    __shared__ float  swsum[4];
    __shared__ double sred[4 * 5];
    __shared__ int    slast;

    int b   = blockIdx.y;
    int tid = threadIdx.x;

    if (blockIdx.x < MCHUNK) {
        int n = blockIdx.x * 256 + tid;
        int m = min(cnt[b], MAXGT);
        if (tid < m) {
            sbox[tid] = gtbox[b * MAXGT + tid];
            sidx[tid] = gtinfo[b * MAXGT + tid].x;
        }
        __syncthreads();

        float v = 0.0f;
        if (n < NCA) {
            size_t rec = (size_t)b * NCA + n;
            float4 pb = boxdec[rec];
            float  pc = confdec[rec];
            float px0 = pb.x - pb.z * 0.5f, px1 = pb.x + pb.z * 0.5f;
            float py0 = pb.y - pb.w * 0.5f, py1 = pb.y + pb.w * 0.5f;
            float areap = pb.z * pb.w;

            float best = 0.0f;
            bool isobj = false;
            for (int k = 0; k < m; k++) {
                float4 g = sbox[k];
                isobj |= (sidx[k] == n);
                float ix = fminf(px1, g.x + g.z * 0.5f) - fmaxf(px0, g.x - g.z * 0.5f);
                float iy = fminf(py1, g.y + g.w * 0.5f) - fmaxf(py0, g.y - g.w * 0.5f);
                float inter = fmaxf(ix, 0.0f) * fmaxf(iy, 0.0f);
                float u = areap + g.z * g.w - inter + 1e-9f;
                best = fmaxf(best, inter * __builtin_amdgcn_rcpf(u));
            }
            if (!isobj && best < 0.6f) v = softplus_fast(pc);
        }

        int lane = tid & 63;
        int wv   = tid >> 6;
        for (int off = 32; off > 0; off >>= 1) v += __shfl_down(v, off);
        if (lane == 0) swsum[wv] = v;
        __syncthreads();
        if (tid == 0)
            partial[b * MCHUNK + blockIdx.x] = swsum[0] + swsum[1] + swsum[2] + swsum[3];
    } else {
        int wv   = tid >> 6;
        int lane = tid & 63;
        int slot = b * MAXGT + (blockIdx.x - MCHUNK) * 4 + wv;
        int k    = slot & (MAXGT - 1);

        float4 resv = make_float4(0.f, 0.f, 0.f, 0.f);
        int m = min(cnt[b], MAXGT);
        if (k < m) {
            float4 g  = gtbox[slot];
            int2 info = gtinfo[slot];
            int n = info.x, cid = info.y;
            size_t rec = (size_t)b * NCA + n;
            const float* cl = pr + rec * CH + 5;

            float x0 = cl[lane];
            float cls = softplus_fast(x0) - (lane == cid ? x0 : 0.0f);
            if (lane < NCLS - 64) {
                float x1 = cl[64 + lane];
                cls += softplus_fast(x1) - ((64 + lane) == cid ? x1 : 0.0f);
            }
            for (int off = 32; off > 0; off >>= 1) cls += __shfl_down(cls, off);

            if (lane == 0) {
                float4 pb = boxdec[rec];
                float  pc = confdec[rec];
                int a    = n % NA;
                int cell = n / NA;
                int gi = cell / GSZ, gj = cell % GSZ;
                float aw = anchors[2 * a], ah = anchors[2 * a + 1];

                float scale = 2.0f - (g.z * (1.0f / 416.0f)) * (g.w * (1.0f / 416.0f));
                float dx = (pb.x * 0.125f - (float)gj) - (g.x * 0.125f - (float)gj);
                float dy = (pb.y * 0.125f - (float)gi) - (g.y * 0.125f - (float)gi);
                float txty = (dx * dx + dy * dy) * scale;

                float rw = __builtin_amdgcn_rcpf(aw), rh = __builtin_amdgcn_rcpf(ah);
                float pwr = fminf(fmaxf(pb.z * rw, 1e-9f), 1e9f);
                float phr = fminf(fmaxf(pb.w * rh, 1e-9f), 1e9f);
                float twr = fminf(fmaxf(g.z  * rw, 1e-9f), 1e9f);
                float thr = fminf(fmaxf(g.w  * rh, 1e-9f), 1e9f);
                float dw = __logf(pwr) - __logf(twr);
                float dh = __logf(phr) - __logf(thr);
                float twth = (dw * dw + dh * dh) * scale;

                float obj = softplus_fast(pc) - pc;
                resv = make_float4(txty, twth, obj, cls);
            }
        }
        if (lane == 0) cls4[slot] = resv;
    }

    // ---- last-block final reduction ----
    __threadfence();                       // release our partial/cls4 writes
    int nblocks = gridDim.x * gridDim.y;
    if (tid == 0)
        slast = (atomicAdd(cnt + 32, 1) == nblocks - 1) ? 1 : 0;
    __syncthreads();
    if (!slast) return;
    __threadfence();                       // acquire all blocks' writes

    const int np = B * MCHUNK;
    const int ns = B * MAXGT;
    double acc[5] = {0, 0, 0, 0, 0};       // txty, twth, noobj, obj, cls
    for (int i = tid; i < np; i += 256) acc[2] += (double)partial[i];
    for (int i = tid; i < ns; i += 256) {
        float4 v = cls4[i];
        acc[0] += (double)v.x; acc[1] += (double)v.y;
        acc[3] += (double)v.z; acc[4] += (double)v.w;
    }
    int lane = tid & 63;
    int wv   = tid >> 6;
#pragma unroll
    for (int i = 0; i < 5; i++) {
        double v = acc[i];
        for (int off = 32; off > 0; off >>= 1) v += __shfl_down(v, off);
        if (lane == 0) sred[wv * 5 + i] = v;
    }
    __syncthreads();
    if (tid == 0) {
        double tot = 0.0;
#pragma unroll
        for (int i = 0; i < 5; i++) {
            double r = (sred[i] + sred[5 + i] + sred[10 + i] + sred[15 + i]) / (double)B;
            out[i] = (float)r;
            tot += r;
        }
        out[5] = (float)tot;
    }
}

extern "C" void kernel_launch(void* const* d_in, const int* in_sizes, int n_in,
                              void* d_out, int out_size, void* d_ws, size_t ws_size,
                              hipStream_t stream) {
    const float* preds   = (const float*)d_in[0];
    const float* targets = (const float*)d_in[1];
    const float* anchors = (const float*)d_in[2];
    float* out = (float*)d_out;

    int B = in_sizes[0] / (NCA * CH);        // 32
    int nrec = B * NCA;                      // 259584
    int scan_blocks = (nrec + 255) / 256;    // 1014
    int np = MCHUNK * B;                     // 1024
    int ns = B * MAXGT;                      // 2048

    // ws layout: cnt(+done ctr) | gtbox | gtinfo | partial | boxdec | confdec | cls4
    char* ws = (char*)d_ws;
    size_t off = 0;
    int*    cnt     = (int*)(ws + off);      off += 256;
    float4* gtbox   = (float4*)(ws + off);   off += (size_t)ns * sizeof(float4);
    int2*   gtinfo  = (int2*)(ws + off);     off += (size_t)ns * sizeof(int2);
    float*  partial = (float*)(ws + off);    off += (size_t)np * sizeof(float);
    off = (off + 15) & ~(size_t)15;
    float4* boxdec  = (float4*)(ws + off);   off += (size_t)nrec * sizeof(float4);
    float*  confdec = (float*)(ws + off);    off += (size_t)nrec * sizeof(float);
    off = (off + 15) & ~(size_t)15;
    float4* cls4    = (float4*)(ws + off);   off += (size_t)ns * sizeof(float4);

    k_init<<<1, 64, 0, stream>>>(cnt);
    k_scan<<<scan_blocks, 256, 0, stream>>>(targets, preds, anchors, nrec, cnt,
                                            gtbox, gtinfo, boxdec, confdec);
    dim3 grid(MCHUNK + CLSU, B);
    k_nc<<<grid, 256, 0, stream>>>(preds, anchors, cnt, gtbox, gtinfo,
                                   boxdec, confdec, partial, cls4, B, out);
}

// Round 5
// 193.098 us; speedup vs baseline: 3.1735x; 1.5090x over previous
//
#include <hip/hip_runtime.h>
#include <math.h>

#define GSZ 52
#define NA 3
#define NCLS 80
#define CH 85                    // 5 + NCLS
#define NCA (GSZ*GSZ*NA)         // 8112 cell-anchors per batch
#define MAXGT 64
#define MCHUNK 32                // noobj units per batch: 32 x 256 = 8192 >= 8112
#define CLSU 16                  // cls units per batch: 16 x 4 waves = 64 slots

// fast softplus: max(x,0) + log(1+exp(-|x|)) with HW-approx exp/log.
__device__ __forceinline__ float softplus_fast(float x) {
    return fmaxf(x, 0.0f) + __logf(1.0f + __expf(-fabsf(x)));
}

__global__ void k_init(int* cnt, int B) {
    if (threadIdx.x < B) cnt[threadIdx.x] = 0;
}

// Rare path: full record read + class scan for an obj record.
__device__ __forceinline__ void emit_gt(const float* __restrict__ tg, int glob,
                                        int* cnt, float4* __restrict__ gtbox,
                                        int2* __restrict__ gtinfo) {
    const float* r = tg + (size_t)glob * CH;
    int b    = glob / NCA;
    int nloc = glob - b * NCA;
    int cid = 0;
#pragma unroll 16
    for (int c = 0; c < NCLS; c++) if (r[5 + c] > 0.5f) cid = c;
    int pos = atomicAdd(cnt + b, 1);
    if (pos < MAXGT) {
        gtbox[b * MAXGT + pos]  = make_float4(r[0], r[1], r[2], r[3]);
        gtinfo[b * MAXGT + pos] = make_int2(nloc, cid);
    }
}

// Role-split scan: each block covers 128 records. Waves 0-1 (threads 0-127)
// load the 4 box logits and decode; waves 2-3 load pred-conf + target-conf
// and handle rare GT emission. Role is wave-uniform (no divergence); twice
// the resident waves of the 1-thread-per-record form, half the dependent
// loads per wave -> more memory-level parallelism on the scattered sectors.
__global__ __launch_bounds__(256) void k_scan(
    const float* __restrict__ tg, const float* __restrict__ pr,
    const float* __restrict__ anchors, int nrec, int* cnt,
    float4* __restrict__ gtbox, int2* __restrict__ gtinfo,
    float4* __restrict__ boxdec, float* __restrict__ confdec) {
    int tid = threadIdx.x;
    int rec = blockIdx.x * 128 + (tid & 127);
    if (rec >= nrec) return;

    const float* rp = pr + (size_t)rec * CH;
    if (tid < 128) {
        float r0 = rp[0], r1 = rp[1], r2 = rp[2], r3 = rp[3];
        int b    = rec / NCA;
        int n    = rec - b * NCA;
        int a    = n % NA;
        int cell = n / NA;
        int gi = cell / GSZ, gj = cell % GSZ;
        float aw = anchors[2 * a], ah = anchors[2 * a + 1];
        float sx = __builtin_amdgcn_rcpf(1.0f + __expf(-r0));
        float sy = __builtin_amdgcn_rcpf(1.0f + __expf(-r1));
        float bx = (sx + (float)gj) * 8.0f;
        float by = (sy + (float)gi) * 8.0f;
        float bw = __expf(r2) * aw;
        float bh = __expf(r3) * ah;
        boxdec[rec] = make_float4(bx, by, bw, bh);
    } else {
        float pc     = rp[4];
        float conf_t = tg[(size_t)rec * CH + 4];
        confdec[rec] = pc;
        if (conf_t > 0.0f) emit_gt(tg, rec, cnt, gtbox, gtinfo);
    }
}

// Fused noobj + cls kernel (R2-proven structure, no device-scope sync).
__global__ __launch_bounds__(256) void k_nc(
    const float* __restrict__ pr,
    const float* __restrict__ anchors,
    const int* __restrict__ cnt,
    const float4* __restrict__ gtbox,
    const int2* __restrict__ gtinfo,
    const float4* __restrict__ boxdec,
    const float* __restrict__ confdec,
    float* __restrict__ partial,
    float4* __restrict__ cls4) {
    __shared__ float4 sbox[MAXGT];
    __shared__ int    sidx[MAXGT];
    __shared__ float  swsum[4];

    int b   = blockIdx.y;
    int tid = threadIdx.x;

    if (blockIdx.x < MCHUNK) {
        int n = blockIdx.x * 256 + tid;
        int m = min(cnt[b], MAXGT);
        if (tid < m) {
            sbox[tid] = gtbox[b * MAXGT + tid];
            sidx[tid] = gtinfo[b * MAXGT + tid].x;
        }
        __syncthreads();

        float v = 0.0f;
        if (n < NCA) {
            size_t rec = (size_t)b * NCA + n;
            float4 pb = boxdec[rec];
            float  pc = confdec[rec];
            float px0 = pb.x - pb.z * 0.5f, px1 = pb.x + pb.z * 0.5f;
            float py0 = pb.y - pb.w * 0.5f, py1 = pb.y + pb.w * 0.5f;
            float areap = pb.z * pb.w;

            float best = 0.0f;
            bool isobj = false;
            for (int k = 0; k < m; k++) {
                float4 g = sbox[k];
                isobj |= (sidx[k] == n);
                float ix = fminf(px1, g.x + g.z * 0.5f) - fmaxf(px0, g.x - g.z * 0.5f);
                float iy = fminf(py1, g.y + g.w * 0.5f) - fmaxf(py0, g.y - g.w * 0.5f);
                float inter = fmaxf(ix, 0.0f) * fmaxf(iy, 0.0f);
                float u = areap + g.z * g.w - inter + 1e-9f;
                best = fmaxf(best, inter * __builtin_amdgcn_rcpf(u));
            }
            if (!isobj && best < 0.6f) v = softplus_fast(pc);
        }

        int lane = tid & 63;
        int wv   = tid >> 6;
        for (int off = 32; off > 0; off >>= 1) v += __shfl_down(v, off);
        if (lane == 0) swsum[wv] = v;
        __syncthreads();
        if (tid == 0)
            partial[b * MCHUNK + blockIdx.x] = swsum[0] + swsum[1] + swsum[2] + swsum[3];
    } else {
        int wv   = tid >> 6;
        int lane = tid & 63;
        int slot = b * MAXGT + (blockIdx.x - MCHUNK) * 4 + wv;
        int k    = slot & (MAXGT - 1);

        float4 resv = make_float4(0.f, 0.f, 0.f, 0.f);
        int m = min(cnt[b], MAXGT);
        if (k < m) {
            float4 g  = gtbox[slot];
            int2 info = gtinfo[slot];
            int n = info.x, cid = info.y;
            size_t rec = (size_t)b * NCA + n;
            const float* cl = pr + rec * CH + 5;

            float x0 = cl[lane];
            float cls = softplus_fast(x0) - (lane == cid ? x0 : 0.0f);
            if (lane < NCLS - 64) {
                float x1 = cl[64 + lane];
                cls += softplus_fast(x1) - ((64 + lane) == cid ? x1 : 0.0f);
            }
            for (int off = 32; off > 0; off >>= 1) cls += __shfl_down(cls, off);

            if (lane == 0) {
                float4 pb = boxdec[rec];
                float  pc = confdec[rec];
                int a    = n % NA;
                int cell = n / NA;
                int gi = cell / GSZ, gj = cell % GSZ;
                float aw = anchors[2 * a], ah = anchors[2 * a + 1];

                float scale = 2.0f - (g.z * (1.0f / 416.0f)) * (g.w * (1.0f / 416.0f));
                float dx = (pb.x * 0.125f - (float)gj) - (g.x * 0.125f - (float)gj);
                float dy = (pb.y * 0.125f - (float)gi) - (g.y * 0.125f - (float)gi);
                float txty = (dx * dx + dy * dy) * scale;

                float rw = __builtin_amdgcn_rcpf(aw), rh = __builtin_amdgcn_rcpf(ah);
                float pwr = fminf(fmaxf(pb.z * rw, 1e-9f), 1e9f);
                float phr = fminf(fmaxf(pb.w * rh, 1e-9f), 1e9f);
                float twr = fminf(fmaxf(g.z  * rw, 1e-9f), 1e9f);
                float thr = fminf(fmaxf(g.w  * rh, 1e-9f), 1e9f);
                float dw = __logf(pwr) - __logf(twr);
                float dh = __logf(phr) - __logf(thr);
                float twth = (dw * dw + dh * dh) * scale;

                float obj = softplus_fast(pc) - pc;
                resv = make_float4(txty, twth, obj, cls);
            }
        }
        if (lane == 0) cls4[slot] = resv;
    }
}

__global__ void k_final(const float* __restrict__ partial, int np,
                        const float4* __restrict__ cls4, int ns,
                        int B, float* __restrict__ out) {
    __shared__ double sred[4 * 5];
    int tid = threadIdx.x;
    double acc[5] = {0, 0, 0, 0, 0};   // txty, twth, noobj, obj, cls
    for (int i = tid; i < np; i += 256) acc[2] += (double)partial[i];
    for (int i = tid; i < ns; i += 256) {
        float4 v = cls4[i];
        acc[0] += (double)v.x; acc[1] += (double)v.y;
        acc[3] += (double)v.z; acc[4] += (double)v.w;
    }
    int lane = tid & 63;
    int wv   = tid >> 6;
#pragma unroll
    for (int i = 0; i < 5; i++) {
        double v = acc[i];
        for (int off = 32; off > 0; off >>= 1) v += __shfl_down(v, off);
        if (lane == 0) sred[wv * 5 + i] = v;
    }
    __syncthreads();
    if (tid == 0) {
        double tot = 0.0;
#pragma unroll
        for (int i = 0; i < 5; i++) {
            double r = (sred[i] + sred[5 + i] + sred[10 + i] + sred[15 + i]) / (double)B;
            out[i] = (float)r;
            tot += r;
        }
        out[5] = (float)tot;
    }
}

extern "C" void kernel_launch(void* const* d_in, const int* in_sizes, int n_in,
                              void* d_out, int out_size, void* d_ws, size_t ws_size,
                              hipStream_t stream) {
    const float* preds   = (const float*)d_in[0];
    const float* targets = (const float*)d_in[1];
    const float* anchors = (const float*)d_in[2];
    float* out = (float*)d_out;

    int B = in_sizes[0] / (NCA * CH);        // 32
    int nrec = B * NCA;                      // 259584
    int scan_blocks = (nrec + 127) / 128;    // 2028
    int np = MCHUNK * B;                     // 1024
    int ns = B * MAXGT;                      // 2048

    // ws layout: cnt | gtbox | gtinfo | partial | boxdec | confdec | cls4
    char* ws = (char*)d_ws;
    size_t off = 0;
    int*    cnt     = (int*)(ws + off);      off += 128;
    float4* gtbox   = (float4*)(ws + off);   off += (size_t)ns * sizeof(float4);
    int2*   gtinfo  = (int2*)(ws + off);     off += (size_t)ns * sizeof(int2);
    float*  partial = (float*)(ws + off);    off += (size_t)np * sizeof(float);
    off = (off + 15) & ~(size_t)15;
    float4* boxdec  = (float4*)(ws + off);   off += (size_t)nrec * sizeof(float4);
    float*  confdec = (float*)(ws + off);    off += (size_t)nrec * sizeof(float);
    off = (off + 15) & ~(size_t)15;
    float4* cls4    = (float4*)(ws + off);   off += (size_t)ns * sizeof(float4);

    k_init<<<1, 64, 0, stream>>>(cnt, B);
    k_scan<<<scan_blocks, 256, 0, stream>>>(targets, preds, anchors, nrec, cnt,
                                            gtbox, gtinfo, boxdec, confdec);
    dim3 grid(MCHUNK + CLSU, B);
    k_nc<<<grid, 256, 0, stream>>>(preds, anchors, cnt, gtbox, gtinfo,
                                   boxdec, confdec, partial, cls4);
    k_final<<<1, 256, 0, stream>>>(partial, np, cls4, ns, B, out);
}